// Round 8
// baseline (95.968 us; speedup 1.0000x reference)
//
#include <hip/hip_runtime.h>
#include <hip/hip_fp16.h>
#include <math.h>

#define VFS_EPS 1e-7f

constexpr int V_ = 8, F_ = 64, H_ = 256, W_ = 256, G_ = 128, S_ = 512;
constexpr int HW_ = H_ * W_;
constexpr int TPX = 512;  // pixels per transpose tile

__device__ __forceinline__ __half2 vfs_uint_as_half2(uint u) {
    union { uint u; __half2 h; } c;
    c.u = u;
    return c.h;
}

// -------- K0: transpose+convert [V][F][HW] f32 -> [V][HW][F] f16 --------
// Validated R4-R7: ~27 us (2KB channel runs in, 64KB contiguous out).
__global__ __launch_bounds__(512) void vfs_transpose_h(const float* __restrict__ src,
                                                       __half* __restrict__ dst) {
    __shared__ ushort L[TPX][64];  // 64 KB
    const int v = blockIdx.y;
    const int p0 = blockIdx.x * TPX;
    const int t = threadIdx.x;
    const float* s = src + (size_t)v * F_ * HW_ + p0;
#pragma unroll 8
    for (int c = 0; c < F_; ++c) {
        const float val = s[(size_t)c * HW_ + t];
        const int os = (c >> 3) ^ (t & 7);
        L[t][os * 8 + (c & 7)] = __half_as_ushort(__float2half(val));
    }
    __syncthreads();
    __half* d = dst + ((size_t)v * HW_ + p0) * F_;
#pragma unroll
    for (int i = 0; i < 8; ++i) {
        const int j = i * 512 + t;
        const int p = j >> 3;
        const int o = j & 7;
        const int os = o ^ (p & 7);
        const uint4 val = *reinterpret_cast<const uint4*>(&L[p][os * 8]);
        *reinterpret_cast<uint4*>(&d[(size_t)j * 8]) = val;
    }
}

// -------- K1 (f16 ws): wave = 1 point; contiguous 256B row-pair segments ----
// Corner addresses are WAVE-UNIFORM (readfirstlane -> SGPR base); lane adds
// only lane*4B. Per (view,row): one 256B load covers both x-corners (2 px x
// 64 ch). __shfl_xor(32) exchanges the two pixels; uniform selects map
// segment positions -> corners (exact under clamping). Lanes<32 produce
// mean, lanes>=32 produce var (duplicate accumulation, split writeback).
__global__ __launch_bounds__(256) void vfs_sampler_h2(
    const __half* __restrict__ feat,
    const float* __restrict__ Km, const float* __restrict__ Em,
    const float* __restrict__ dst, const float* __restrict__ grids,
    const float* __restrict__ vis, const float* __restrict__ normals,
    const float* __restrict__ cc, float* __restrict__ out) {
    __shared__ float4 wp[64][8];   // {x0 bits, y0 bits, wx, wy} per (s_local, view)
    __shared__ float wv[64][8];    // normalized view weight
    __shared__ float stgM[64][65]; // mean staging
    __shared__ float stgV[64][65]; // var staging

    const int g = blockIdx.x >> 3;
    const int sb = (blockIdx.x & 7) * 64;
    const int t = threadIdx.x;
    const int wave = t >> 6;
    const int lane = t & 63;

    // ---- Phase A: lane = (point8, view8); params + normalized weights ----
    {
        const int vL = lane & 7;
        const int pL = lane >> 3;
        const float nx = normals[g * 3 + 0];
        const float ny = normals[g * 3 + 1];
        const float nz = normals[g * 3 + 2];
#pragma unroll
        for (int grp = 0; grp < 2; ++grp) {
            const int sl = wave * 16 + grp * 8 + pL;
            const int s = sb + sl;
            const float px = grids[(g * 3 + 0) * S_ + s];
            const float py = grids[(g * 3 + 1) * S_ + s];
            const float pz = grids[(g * 3 + 2) * S_ + s];
            const float* Ev = Em + vL * 12;
            const float pi0 = Ev[0] * px + Ev[1] * py + Ev[2] * pz + Ev[3];
            const float pi1 = Ev[4] * px + Ev[5] * py + Ev[6] * pz + Ev[7];
            float z = Ev[8] * px + Ev[9] * py + Ev[10] * pz + Ev[11];
            if (fabsf(z) < VFS_EPS) z = 1.0f;
            const float xn = pi0 / z;
            const float yn = pi1 / z;
            const float r2 = xn * xn + yn * yn;
            const float fd = 1.0f + dst[vL * 2 + 0] * r2 + dst[vL * 2 + 1] * r2 * r2;
            const float xd = xn * fd, yd = yn * fd;
            const float* Kv = Km + vL * 9;
            const float pk0 = Kv[0] * xd + Kv[1] * yd + Kv[2];
            const float pk1 = Kv[3] * xd + Kv[4] * yd + Kv[5];
            const float u = 2.0f * pk0 / (W_ - 1.0f) - 1.0f;
            const float vq = 2.0f * pk1 / (H_ - 1.0f) - 1.0f;
            const bool inside = (u >= -1.0f) && (u <= 1.0f) && (vq >= -1.0f) && (vq <= 1.0f);
            const float x = (u + 1.0f) * (W_ * 0.5f) - 0.5f;
            const float y = (vq + 1.0f) * (H_ * 0.5f) - 0.5f;
            const float x0f = floorf(x), y0f = floorf(y);
            const float wx = x - x0f, wy = y - y0f;
            const int x0 = (int)x0f, y0 = (int)y0f;
            const float dx = px - cc[vL * 3 + 0];
            const float dy = py - cc[vL * 3 + 1];
            const float dz = pz - cc[vL * 3 + 2];
            float nrm = sqrtf(dx * dx + dy * dy + dz * dz);
            nrm = fmaxf(nrm, 1e-12f);
            float cosv = (dx * nx + dy * ny + dz * nz) / nrm;
            cosv = fminf(cosv, 0.0f);
            const float wraw = vis[vL * G_ + g] * (-cosv) * (inside ? 1.0f : 0.0f);
            const float bx = 50.0f * wraw;
            float w = (bx > 5.0f) ? wraw : (log1pf(expf(bx)) * (1.0f / 50.0f));
            float wsum = w;
            wsum += __shfl_xor(wsum, 1);
            wsum += __shfl_xor(wsum, 2);
            wsum += __shfl_xor(wsum, 4);
            w = w / wsum;
            wp[sl][vL] = make_float4(__int_as_float(x0), __int_as_float(y0), wx, wy);
            wv[sl][vL] = w;
        }
    }
    __syncthreads();

    // ---- Phase B: wave = 1 point, lane = (x-corner, ch-pair) ----
    const int hs = lane >> 5;   // which pixel of the segment this lane holds
    const int cp = lane & 31;   // channel pair -> channels 2cp, 2cp+1
    const uint* fp = reinterpret_cast<const uint*>(feat);

    for (int j = 0; j < 16; ++j) {
        const int sl = wave * 16 + j;
        // ---- batch-issue: 16 segment loads (8 views x 2 rows), SGPR bases ----
        uint u0[8], u1[8];
#pragma unroll
        for (int v = 0; v < 8; ++v) {
            const float4 q = wp[sl][v];  // wave-uniform broadcast
            const int x0 = __builtin_amdgcn_readfirstlane(__float_as_int(q.x));
            const int y0 = __builtin_amdgcn_readfirstlane(__float_as_int(q.y));
            const int xs = min(max(x0, 0), W_ - 2);
            const int yc0 = min(max(y0, 0), H_ - 1);
            const int yc1 = min(max(y0 + 1, 0), H_ - 1);
            u0[v] = fp[((uint)(v * HW_ + yc0 * W_ + xs) << 5) + (uint)lane];
            u1[v] = fp[((uint)(v * HW_ + yc1 * W_ + xs) << 5) + (uint)lane];
        }
        // ---- consume: exchange halves, select corners, bilinear, accumulate ----
        float mx = 0.f, my = 0.f, qx = 0.f, qy = 0.f;
#pragma unroll
        for (int v = 0; v < 8; ++v) {
            const float4 q = wp[sl][v];
            const float w = wv[sl][v];
            const int x0 = __builtin_amdgcn_readfirstlane(__float_as_int(q.x));
            const int y0 = __builtin_amdgcn_readfirstlane(__float_as_int(q.y));
            const float wx = q.z, wy = q.w;
            const int xs = min(max(x0, 0), W_ - 2);
            const int p0 = min(max(x0, 0), W_ - 1) - xs;      // 0/1, uniform
            const int p1 = min(max(x0 + 1, 0), W_ - 1) - xs;  // 0/1, uniform
            const uint o0 = (uint)__shfl_xor((int)u0[v], 32);
            const uint o1 = (uint)__shfl_xor((int)u1[v], 32);
            const uint c00 = (p0 == hs) ? u0[v] : o0;
            const uint c01 = (p1 == hs) ? u0[v] : o0;
            const uint c10 = (p0 == hs) ? u1[v] : o1;
            const uint c11 = (p1 == hs) ? u1[v] : o1;
            const bool vx0 = (x0 >= 0) & (x0 < W_);
            const bool vx1 = (x0 >= -1) & (x0 < W_ - 1);
            const bool vy0 = (y0 >= 0) & (y0 < H_);
            const bool vy1 = (y0 >= -1) & (y0 < H_ - 1);
            const float f00 = (vx0 & vy0) ? (1.f - wx) * (1.f - wy) : 0.f;
            const float f01 = (vx1 & vy0) ? wx * (1.f - wy) : 0.f;
            const float f10 = (vx0 & vy1) ? (1.f - wx) * wy : 0.f;
            const float f11 = (vx1 & vy1) ? wx * wy : 0.f;
            const float2 g00 = __half22float2(vfs_uint_as_half2(c00));
            const float2 g01 = __half22float2(vfs_uint_as_half2(c01));
            const float2 g10 = __half22float2(vfs_uint_as_half2(c10));
            const float2 g11 = __half22float2(vfs_uint_as_half2(c11));
            const float fex = g00.x * f00 + g01.x * f01 + g10.x * f10 + g11.x * f11;
            const float fey = g00.y * f00 + g01.y * f01 + g10.y * f10 + g11.y * f11;
            mx += w * fex;
            qx += w * fex * fex;
            my += w * fey;
            qy += w * fey * fey;
        }
        if (hs == 0) {
            stgM[sl][2 * cp + 0] = mx;
            stgM[sl][2 * cp + 1] = my;
        } else {
            stgV[sl][2 * cp + 0] = qx - mx * mx;
            stgV[sl][2 * cp + 1] = qy - my * my;
        }
    }
    __syncthreads();

    // ---- coalesced write-out ----
#pragma unroll
    for (int i = 0; i < 16; ++i) {
        const int e = t + i * 256;
        const int f = e >> 6;
        const int sl = e & 63;
        out[((size_t)(g * 2 * F_ + f)) * S_ + sb + sl] = stgM[sl][f];
    }
#pragma unroll
    for (int i = 0; i < 16; ++i) {
        const int e = t + i * 256;
        const int f = e >> 6;
        const int sl = e & 63;
        out[((size_t)(g * 2 * F_ + F_ + f)) * S_ + sb + sl] = stgV[sl][f];
    }
}

// -------- K1 fallback (raw f32 layout), from R2 (validated) --------
__global__ __launch_bounds__(256) void vfs_sampler_f32(
    const float* __restrict__ feat,
    const float* __restrict__ Km, const float* __restrict__ Em,
    const float* __restrict__ dst, const float* __restrict__ grids,
    const float* __restrict__ vis, const float* __restrict__ normals,
    const float* __restrict__ cc, float* __restrict__ out) {
    __shared__ float4 wp[64][8];
    __shared__ float wv[64][8];
    __shared__ float stg[64][65];

    const int g = blockIdx.x >> 3;
    const int sb = (blockIdx.x & 7) * 64;
    const int t = threadIdx.x;
    const int wave = t >> 6;
    const int lane = t & 63;
    const int vL = lane & 7;
    const int pL = lane >> 3;

    const float nx = normals[g * 3 + 0];
    const float ny = normals[g * 3 + 1];
    const float nz = normals[g * 3 + 2];

#pragma unroll
    for (int grp = 0; grp < 2; ++grp) {
        const int sl = wave * 16 + grp * 8 + pL;
        const int s = sb + sl;
        const float px = grids[(g * 3 + 0) * S_ + s];
        const float py = grids[(g * 3 + 1) * S_ + s];
        const float pz = grids[(g * 3 + 2) * S_ + s];
        const float* Ev = Em + vL * 12;
        const float pi0 = Ev[0] * px + Ev[1] * py + Ev[2] * pz + Ev[3];
        const float pi1 = Ev[4] * px + Ev[5] * py + Ev[6] * pz + Ev[7];
        float z = Ev[8] * px + Ev[9] * py + Ev[10] * pz + Ev[11];
        if (fabsf(z) < VFS_EPS) z = 1.0f;
        const float xn = pi0 / z;
        const float yn = pi1 / z;
        const float r2 = xn * xn + yn * yn;
        const float fd = 1.0f + dst[vL * 2 + 0] * r2 + dst[vL * 2 + 1] * r2 * r2;
        const float xd = xn * fd, yd = yn * fd;
        const float* Kv = Km + vL * 9;
        const float pk0 = Kv[0] * xd + Kv[1] * yd + Kv[2];
        const float pk1 = Kv[3] * xd + Kv[4] * yd + Kv[5];
        const float u = 2.0f * pk0 / (W_ - 1.0f) - 1.0f;
        const float vq = 2.0f * pk1 / (H_ - 1.0f) - 1.0f;
        const bool inside = (u >= -1.0f) && (u <= 1.0f) && (vq >= -1.0f) && (vq <= 1.0f);
        const float x = (u + 1.0f) * (W_ * 0.5f) - 0.5f;
        const float y = (vq + 1.0f) * (H_ * 0.5f) - 0.5f;
        const float x0f = floorf(x), y0f = floorf(y);
        const float wx = x - x0f, wy = y - y0f;
        const int x0 = (int)x0f, y0 = (int)y0f;
        const float dx = px - cc[vL * 3 + 0];
        const float dy = py - cc[vL * 3 + 1];
        const float dz = pz - cc[vL * 3 + 2];
        float nrm = sqrtf(dx * dx + dy * dy + dz * dz);
        nrm = fmaxf(nrm, 1e-12f);
        float cosv = (dx * nx + dy * ny + dz * nz) / nrm;
        cosv = fminf(cosv, 0.0f);
        const float wraw = vis[vL * G_ + g] * (-cosv) * (inside ? 1.0f : 0.0f);
        const float bx = 50.0f * wraw;
        float w = (bx > 5.0f) ? wraw : (log1pf(expf(bx)) * (1.0f / 50.0f));
        float wsum = w;
        wsum += __shfl_xor(wsum, 1);
        wsum += __shfl_xor(wsum, 2);
        wsum += __shfl_xor(wsum, 4);
        w = w / wsum;
        wp[sl][vL] = make_float4(__int_as_float(x0), __int_as_float(y0), wx, wy);
        wv[sl][vL] = w;
    }
    __syncthreads();

    float mean[16], var[16];
#pragma unroll 2
    for (int j = 0; j < 16; ++j) {
        const int sl = wave * 16 + j;
        float m = 0.0f, m2 = 0.0f;
#pragma unroll
        for (int v = 0; v < 8; ++v) {
            const float4 q = wp[sl][v];
            const float w = wv[sl][v];
            const int x0 = __float_as_int(q.x);
            const int y0 = __float_as_int(q.y);
            const float wx = q.z, wy = q.w;
            const bool vx0 = (x0 >= 0) & (x0 < W_);
            const bool vx1 = (x0 >= -1) & (x0 < W_ - 1);
            const bool vy0 = (y0 >= 0) & (y0 < H_);
            const bool vy1 = (y0 >= -1) & (y0 < H_ - 1);
            const int xc0 = min(max(x0, 0), W_ - 1);
            const int xc1 = min(max(x0 + 1, 0), W_ - 1);
            const int yc0 = min(max(y0, 0), H_ - 1);
            const int yc1 = min(max(y0 + 1, 0), H_ - 1);
            const float* base = feat + (size_t)v * ((size_t)HW_ * F_) + (size_t)lane * HW_;
            const float g00 = base[(size_t)(yc0 * W_ + xc0)];
            const float g01 = base[(size_t)(yc0 * W_ + xc1)];
            const float g10 = base[(size_t)(yc1 * W_ + xc0)];
            const float g11 = base[(size_t)(yc1 * W_ + xc1)];
            const float f00 = (vx0 & vy0) ? (1.f - wx) * (1.f - wy) : 0.f;
            const float f01 = (vx1 & vy0) ? wx * (1.f - wy) : 0.f;
            const float f10 = (vx0 & vy1) ? (1.f - wx) * wy : 0.f;
            const float f11 = (vx1 & vy1) ? wx * wy : 0.f;
            const float fe = g00 * f00 + g01 * f01 + g10 * f10 + g11 * f11;
            m += w * fe;
            m2 += w * fe * fe;
        }
        mean[j] = m;
        var[j] = m2 - m * m;
    }

#pragma unroll
    for (int j = 0; j < 16; ++j) stg[wave * 16 + j][lane] = mean[j];
    __syncthreads();
#pragma unroll
    for (int i = 0; i < 16; ++i) {
        const int e = t + i * 256;
        const int f = e >> 6;
        const int sl = e & 63;
        out[((size_t)(g * 2 * F_ + f)) * S_ + sb + sl] = stg[sl][f];
    }
    __syncthreads();
#pragma unroll
    for (int j = 0; j < 16; ++j) stg[wave * 16 + j][lane] = var[j];
    __syncthreads();
#pragma unroll
    for (int i = 0; i < 16; ++i) {
        const int e = t + i * 256;
        const int f = e >> 6;
        const int sl = e & 63;
        out[((size_t)(g * 2 * F_ + F_ + f)) * S_ + sb + sl] = stg[sl][f];
    }
}

extern "C" void kernel_launch(void* const* d_in, const int* in_sizes, int n_in,
                              void* d_out, int out_size, void* d_ws, size_t ws_size,
                              hipStream_t stream) {
    const float* fm      = (const float*)d_in[0]; // [1][8][64][256][256]
    const float* Km      = (const float*)d_in[1]; // [1][8][3][3]
    const float* Em      = (const float*)d_in[2]; // [1][8][3][4]
    const float* dist    = (const float*)d_in[3]; // [1][8][2]
    const float* grids   = (const float*)d_in[4]; // [1][128][3][8][8][8]
    const float* vis     = (const float*)d_in[5]; // [1][8][128]
    const float* normals = (const float*)d_in[6]; // [1][128][3]
    const float* cc      = (const float*)d_in[7]; // [1][8][3]
    float* out           = (float*)d_out;         // [1][128][128][8][8][8]

    const size_t tsize = (size_t)V_ * F_ * HW_ * sizeof(__half); // 67 MB
    if (ws_size >= tsize) {
        vfs_transpose_h<<<dim3(HW_ / TPX, V_), 512, 0, stream>>>(fm, (__half*)d_ws);
        vfs_sampler_h2<<<G_ * 8, 256, 0, stream>>>((const __half*)d_ws, Km, Em, dist,
                                                   grids, vis, normals, cc, out);
    } else {
        vfs_sampler_f32<<<G_ * 8, 256, 0, stream>>>(fm, Km, Em, dist,
                                                    grids, vis, normals, cc, out);
    }
}